// Round 2
// baseline (1283.463 us; speedup 1.0000x reference)
//
#include <hip/hip_runtime.h>

#define H 512
#define TSTEPS 196
#define FLEN 784
#define NBATCH 256

// workspace layout (floats):
//   [0)        WT_h2h1  512*512   (WT[k*512+j] = W[j*512+k])
//   [262144)   WT_i2h2  512*512
//   [524288)   WT_h2h2  512*512
//   [786432)   WT_i2h3  512*512
//   [1048576)  m1T      196*512   (mT[t*512+j] = m[j*784+t])
//   [1148928)  m2T      196*512
//   [1249280)  m3T      196*512

__global__ void transpose4(const float* __restrict__ a,
                           const float* __restrict__ b,
                           const float* __restrict__ c,
                           const float* __restrict__ d,
                           float* __restrict__ ws)
{
    __shared__ float tile[32][33];
    const float* src = (blockIdx.z == 0) ? a : (blockIdx.z == 1) ? b
                     : (blockIdx.z == 2) ? c : d;
    float* dst = ws + (size_t)blockIdx.z * (H * H);
    int bx = blockIdx.x * 32, by = blockIdx.y * 32;
    int tx = threadIdx.x, ty = threadIdx.y;
    for (int r = ty; r < 32; r += 8)
        tile[r][tx] = src[(by + r) * H + bx + tx];
    __syncthreads();
    for (int r = ty; r < 32; r += 8)
        dst[(bx + r) * H + by + tx] = tile[tx][r];
}

__global__ void maskT3(const float* __restrict__ m1, const float* __restrict__ m2,
                       const float* __restrict__ m3, float* __restrict__ mt)
{
    int idx = blockIdx.x * 256 + threadIdx.x;
    if (idx >= TSTEPS * H) return;
    const float* src = (blockIdx.z == 0) ? m1 : (blockIdx.z == 1) ? m2 : m3;
    float* dst = mt + (size_t)blockIdx.z * (TSTEPS * H);
    int t = idx >> 9, j = idx & (H - 1);
    dst[idx] = src[j * FLEN + t];
}

// h[j] += sum over active k of WT[k][j].
// WTj = WT + j (pre-biased); list holds (k<<9) element offsets.
// 16 independent accumulators -> 16 loads in flight per wave (latency hiding).
__device__ __forceinline__ float gather(const float* __restrict__ WTj,
                                        const int* __restrict__ list,
                                        int nact)
{
    float a[16];
#pragma unroll
    for (int u = 0; u < 16; ++u) a[u] = 0.0f;
    int i = 0;
    for (; i + 16 <= nact; i += 16) {
#pragma unroll
        for (int u = 0; u < 16; ++u)
            a[u] += WTj[list[i + u]];
    }
    for (; i < nact; ++i)
        a[0] += WTj[list[i]];
    float s = 0.0f;
#pragma unroll
    for (int u = 0; u < 16; ++u) s += a[u];
    return s;
}

__global__ __launch_bounds__(512)
void lsnn_main(const float* __restrict__ x,
               const float* __restrict__ Wi1,
               const float* __restrict__ bi1, const float* __restrict__ bh1,
               const float* __restrict__ bi2, const float* __restrict__ bh2,
               const float* __restrict__ bi3,
               const float* __restrict__ Wo,  const float* __restrict__ bo,
               const float* __restrict__ tau1, const float* __restrict__ tau2,
               const float* __restrict__ tau3,
               const float* __restrict__ ws,
               float* __restrict__ out)
{
    const float* m1T  = ws + 1048576;
    const float* m2T  = m1T + TSTEPS * H;
    const float* m3T  = m2T + TSTEPS * H;

    const int n = blockIdx.x;
    const int j = threadIdx.x;
    const int lane = j & 63, wid = j >> 6;

    // pre-biased per-thread weight pointers
    const float* WT1j  = ws + j;            // W_h2h1^T
    const float* WTi2j = ws + 262144 + j;   // W_i2h2^T
    const float* WTh2j = ws + 524288 + j;   // W_h2h2^T
    const float* WTi3j = ws + 786432 + j;   // W_i2h3^T

    __shared__ int list1[H], list2[H];
    __shared__ int wcnt[8];
    __shared__ float c3s[H];

    float4 wi = reinterpret_cast<const float4*>(Wi1)[j];
    float bs1 = bi1[j] + bh1[j];
    float bs2 = bi2[j] + bh2[j];
    float bs3 = bi3[j];
    float ro1 = expf(-1.0f / tau1[j]);
    float ro2 = expf(-1.0f / tau2[j]);
    float ro3 = expf(-1.0f / tau3[j]);
    float omr1 = 1.0f - ro1, omr2 = 1.0f - ro2, omr3 = 1.0f - ro3;
    const float alpha = expf(-1.0f / 20.0f);
    const float oma = 1.0f - alpha;

    float mem1 = 0.f, mem2 = 0.f, mem3 = 0.f;
    float b1 = 0.01f, b2 = 0.01f, b3 = 0.01f;
    float s1 = 0.f, s2 = 0.f, s3 = 0.f;
    float cnt3 = 0.f;
    int na1 = 0, na2 = 0;   // current valid lengths of list1/list2

    const float* xr = x + n * FLEN;

    for (int t = 0; t < TSTEPS; ++t) {
        int base = (t < 48) ? (4 * t) : (FLEN - 4);
        float4 xv = *reinterpret_cast<const float4*>(xr + base);
        float mk1 = m1T[t * H + j];
        float mk2 = m2T[t * H + j];
        float mk3 = m3T[t * H + j];

        // ---- layer 1: h1 = x@Wi1^T + bi1 + s1_old@Wh1^T + bh1 ----
        float h1 = wi.x * xv.x + wi.y * xv.y + wi.z * xv.z + wi.w * xv.w + bs1
                 + gather(WT1j, list1, na1);
        b1 = ro1 * b1 + omr1 * s1;
        float Bth1 = 0.01f + 1.8f * b1;
        float nm1 = mem1 * alpha + oma * h1 - Bth1 * s1;
        mem1 = (mk1 == 0.0f) ? mem1 : nm1;
        s1 = (mem1 - Bth1 > 0.0f) ? mk1 : 0.0f;

        // ---- rebuild list1 (2 barriers) ----
        unsigned long long ball1 = __ballot(s1 != 0.0f);
        if (lane == 0) wcnt[wid] = __popcll(ball1);
        __syncthreads();                 // B1: gather1 readers done, wcnt visible
        {
            int basew = 0, tot = 0;
#pragma unroll
            for (int w = 0; w < 8; ++w) {
                int c = wcnt[w];
                if (w < wid) basew += c;
                tot += c;
            }
            if (s1 != 0.0f) {
                int pre = __popcll(ball1 & ((1ull << lane) - 1ull));
                list1[basew + pre] = j << 9;
            }
            na1 = tot;
        }
        __syncthreads();                 // B2: new list1 ready

        // ---- layer 2: h2 = s1_new@Wi2^T + bi2 + s2_old@Wh2^T + bh2 ----
        float h2 = bs2 + gather(WTi2j, list1, na1)
                       + gather(WTh2j, list2, na2);
        b2 = ro2 * b2 + omr2 * s2;
        float Bth2 = 0.01f + 1.8f * b2;
        float nm2 = mem2 * alpha + oma * h2 - Bth2 * s2;
        mem2 = (mk2 == 0.0f) ? mem2 : nm2;
        s2 = (mem2 - Bth2 > 0.0f) ? mk2 : 0.0f;

        // ---- rebuild list2 (2 barriers) ----
        unsigned long long ball2 = __ballot(s2 != 0.0f);
        if (lane == 0) wcnt[wid] = __popcll(ball2);
        __syncthreads();                 // B3: gather2 readers done, wcnt visible
        {
            int basew = 0, tot = 0;
#pragma unroll
            for (int w = 0; w < 8; ++w) {
                int c = wcnt[w];
                if (w < wid) basew += c;
                tot += c;
            }
            if (s2 != 0.0f) {
                int pre = __popcll(ball2 & ((1ull << lane) - 1ull));
                list2[basew + pre] = j << 9;
            }
            na2 = tot;
        }
        __syncthreads();                 // B4: new list2 ready

        // ---- layer 3: h3 = s2_new@Wi3^T + bi3 ----
        float h3 = bs3 + gather(WTi3j, list2, na2);
        b3 = ro3 * b3 + omr3 * s3;
        float Bth3 = 0.01f + 1.8f * b3;
        float nm3 = mem3 * alpha + oma * h3 - Bth3 * s3;
        mem3 = (mk3 == 0.0f) ? mem3 : nm3;
        s3 = (mem3 - Bth3 > 0.0f) ? mk3 : 0.0f;
        cnt3 += s3;   // defer output GEMV: acc = Wo @ sum_t s3(t)
    }

    // ---- output: out[n,o] = (Wo[o,:]·cnt3 + T*bo[o]) / T ----
    c3s[j] = cnt3;
    __syncthreads();
    for (int o = wid; o < 10; o += 8) {
        float p = 0.0f;
        for (int i = lane; i < H; i += 64)
            p += Wo[o * H + i] * c3s[i];
        for (int off = 32; off > 0; off >>= 1)
            p += __shfl_down(p, off);
        if (lane == 0)
            out[n * 10 + o] = (p + 196.0f * bo[o]) / 196.0f;
    }
}

extern "C" void kernel_launch(void* const* d_in, const int* in_sizes, int n_in,
                              void* d_out, int out_size, void* d_ws, size_t ws_size,
                              hipStream_t stream)
{
    const float* x    = (const float*)d_in[0];
    const float* Wi1  = (const float*)d_in[1];
    const float* bi1  = (const float*)d_in[2];
    const float* Wh1  = (const float*)d_in[3];
    const float* bh1  = (const float*)d_in[4];
    const float* Wi2  = (const float*)d_in[5];
    const float* bi2  = (const float*)d_in[6];
    const float* Wh2  = (const float*)d_in[7];
    const float* bh2  = (const float*)d_in[8];
    const float* Wi3  = (const float*)d_in[9];
    const float* bi3  = (const float*)d_in[10];
    const float* Wo   = (const float*)d_in[11];
    const float* bo   = (const float*)d_in[12];
    const float* tau1 = (const float*)d_in[13];
    const float* tau2 = (const float*)d_in[14];
    const float* tau3 = (const float*)d_in[15];
    const float* m1   = (const float*)d_in[16];
    const float* m2   = (const float*)d_in[17];
    const float* m3   = (const float*)d_in[18];

    float* ws  = (float*)d_ws;
    float* out = (float*)d_out;

    // pre-pass: transpose the 4 recurrent/ff matrices + 3 masks into ws
    transpose4<<<dim3(16, 16, 4), dim3(32, 8, 1), 0, stream>>>(Wh1, Wi2, Wh2, Wi3, ws);
    maskT3<<<dim3((TSTEPS * H + 255) / 256, 1, 3), 256, 0, stream>>>(m1, m2, m3, ws + 1048576);

    // main persistent kernel: 1 sample per workgroup (256 WGs, 512 thr)
    lsnn_main<<<NBATCH, H, 0, stream>>>(x, Wi1, bi1, bh1, bi2, bh2, bi3,
                                        Wo, bo, tau1, tau2, tau3, ws, out);
}

// Round 3
// 837.154 us; speedup vs baseline: 1.5331x; 1.5331x over previous
//
#include <hip/hip_runtime.h>

#define H 512
#define TSTEPS 196
#define FLEN 784
#define NBATCH 256

// workspace layout (floats):
//   [0)        WT_h2h1  512*512   (WT[k*512+j] = W[j*512+k])
//   [262144)   WT_i2h2  512*512
//   [524288)   WT_h2h2  512*512
//   [786432)   WT_i2h3  512*512
//   [1048576)  m1T      196*512   (mT[t*512+j] = m[j*784+t])
//   [1148928)  m2T      196*512
//   [1249280)  m3T      196*512

__global__ void transpose4(const float* __restrict__ a,
                           const float* __restrict__ b,
                           const float* __restrict__ c,
                           const float* __restrict__ d,
                           float* __restrict__ ws)
{
    __shared__ float tile[32][33];
    const float* src = (blockIdx.z == 0) ? a : (blockIdx.z == 1) ? b
                     : (blockIdx.z == 2) ? c : d;
    float* dst = ws + (size_t)blockIdx.z * (H * H);
    int bx = blockIdx.x * 32, by = blockIdx.y * 32;
    int tx = threadIdx.x, ty = threadIdx.y;
    for (int r = ty; r < 32; r += 8)
        tile[r][tx] = src[(by + r) * H + bx + tx];
    __syncthreads();
    for (int r = ty; r < 32; r += 8)
        dst[(bx + r) * H + by + tx] = tile[tx][r];
}

__global__ void maskT3(const float* __restrict__ m1, const float* __restrict__ m2,
                       const float* __restrict__ m3, float* __restrict__ mt)
{
    int idx = blockIdx.x * 256 + threadIdx.x;
    if (idx >= TSTEPS * H) return;
    const float* src = (blockIdx.z == 0) ? m1 : (blockIdx.z == 1) ? m2 : m3;
    float* dst = mt + (size_t)blockIdx.z * (TSTEPS * H);
    int t = idx >> 9, j = idx & (H - 1);
    dst[idx] = src[j * FLEN + t];
}

// sum over list[i], i in [lo,hi), of WTj[list[i]]  (list holds k<<9 offsets;
// WTj pre-biased by j). 8 independent accumulators; final partial block is
// PREDICATED (clamped index + select) so there is never a serial tail chain.
__device__ __forceinline__ float gather8(const float* __restrict__ WTj,
                                         const int* __restrict__ list,
                                         int lo, int hi)
{
    float a[8];
#pragma unroll
    for (int u = 0; u < 8; ++u) a[u] = 0.0f;
    int i = lo;
    for (; i + 8 <= hi; i += 8) {
#pragma unroll
        for (int u = 0; u < 8; ++u)
            a[u] += WTj[list[i + u]];
    }
    if (i < hi) {
        int last = hi - 1;
#pragma unroll
        for (int u = 0; u < 8; ++u) {
            int idx = i + u;
            float v = WTj[list[idx < last ? idx : last]];
            a[u] += (idx < hi) ? v : 0.0f;
        }
    }
    return ((a[0] + a[1]) + (a[2] + a[3])) + ((a[4] + a[5]) + (a[6] + a[7]));
}

__global__ __launch_bounds__(1024)
void lsnn_main(const float* __restrict__ x,
               const float* __restrict__ Wi1,
               const float* __restrict__ bi1, const float* __restrict__ bh1,
               const float* __restrict__ bi2, const float* __restrict__ bh2,
               const float* __restrict__ bi3,
               const float* __restrict__ Wo,  const float* __restrict__ bo,
               const float* __restrict__ tau1, const float* __restrict__ tau2,
               const float* __restrict__ tau3,
               const float* __restrict__ ws,
               float* __restrict__ out)
{
    const float* m1T  = ws + 1048576;
    const float* m2T  = m1T + TSTEPS * H;
    const float* m3T  = m2T + TSTEPS * H;

    const int n    = blockIdx.x;
    const int tid  = threadIdx.x;
    const int j    = tid & (H - 1);
    const int half = tid >> 9;           // 0: update-half, 1: helper-half
    const int lane = tid & 63;
    const int wid8 = (tid >> 6) & 7;     // wave id within the half

    // pre-biased per-thread weight pointers
    const float* WT1j  = ws + j;            // W_h2h1^T
    const float* WTi2j = ws + 262144 + j;   // W_i2h2^T
    const float* WTh2j = ws + 524288 + j;   // W_h2h2^T
    const float* WTi3j = ws + 786432 + j;   // W_i2h3^T

    __shared__ int   list1[H], list2[H];
    __shared__ float part[3][H];        // rotating partial buffers (L1,L2,L3)
    __shared__ int   wcnt[8];

    float4 wi = reinterpret_cast<const float4*>(Wi1)[j];
    float bs1 = bi1[j] + bh1[j];
    float bs2 = bi2[j] + bh2[j];
    float bs3 = bi3[j];
    float ro1 = expf(-1.0f / tau1[j]);
    float ro2 = expf(-1.0f / tau2[j]);
    float ro3 = expf(-1.0f / tau3[j]);
    float omr1 = 1.0f - ro1, omr2 = 1.0f - ro2, omr3 = 1.0f - ro3;
    const float alpha = expf(-1.0f / 20.0f);
    const float oma = 1.0f - alpha;

    float mem1 = 0.f, mem2 = 0.f, mem3 = 0.f;
    float b1 = 0.01f, b2 = 0.01f, b3 = 0.01f;
    float s1 = 0.f, s2 = 0.f, s3 = 0.f;
    float cnt3 = 0.f;
    int na1 = 0, na2 = 0;               // valid lengths of list1/list2

    const float* xr = x + n * FLEN;

    for (int t = 0; t < TSTEPS; ++t) {
        int base = (t < 48) ? (4 * t) : (FLEN - 4);
        float4 xv = *reinterpret_cast<const float4*>(xr + base);
        float mk1 = m1T[t * H + j];
        float mk2 = m2T[t * H + j];
        float mk3 = m3T[t * H + j];

        // ======== layer 1: h1 = x@Wi1^T + bs1 + s1_old@Wh1^T ========
        int sp1 = na1 >> 1;
        float g1 = half ? gather8(WT1j, list1, sp1, na1)
                        : gather8(WT1j, list1, 0, sp1);
        if (half) part[0][j] = g1;
        __syncthreads();                                        // B1
        unsigned long long ball = 0;
        if (!half) {
            float h1 = wi.x * xv.x + wi.y * xv.y + wi.z * xv.z + wi.w * xv.w
                     + bs1 + g1 + part[0][j];
            b1 = ro1 * b1 + omr1 * s1;
            float Bth = 0.01f + 1.8f * b1;
            float nm = mem1 * alpha + oma * h1 - Bth * s1;
            mem1 = (mk1 == 0.0f) ? mem1 : nm;
            s1 = (mem1 - Bth > 0.0f) ? mk1 : 0.0f;
            ball = __ballot(s1 != 0.0f);
            if (lane == 0) wcnt[wid8] = __popcll(ball);
        }
        __syncthreads();                                        // B2
        {
            int basew = 0, tot = 0;
#pragma unroll
            for (int w = 0; w < 8; ++w) {
                int c = wcnt[w];
                if (w < wid8) basew += c;
                tot += c;
            }
            if (!half && s1 != 0.0f) {
                int pre = __popcll(ball & ((1ull << lane) - 1ull));
                list1[basew + pre] = j << 9;
            }
            na1 = tot;
        }
        __syncthreads();                                        // B3

        // ======== layer 2: h2 = s1_new@Wi2^T + bs2 + s2_old@Wh2^T ========
        int sp1n = na1 >> 1, sp2 = na2 >> 1;
        float g2;
        if (half) g2 = gather8(WTi2j, list1, sp1n, na1)
                     + gather8(WTh2j, list2, sp2, na2);
        else      g2 = gather8(WTi2j, list1, 0, sp1n)
                     + gather8(WTh2j, list2, 0, sp2);
        if (half) part[1][j] = g2;
        __syncthreads();                                        // B4
        if (!half) {
            float h2 = bs2 + g2 + part[1][j];
            b2 = ro2 * b2 + omr2 * s2;
            float Bth = 0.01f + 1.8f * b2;
            float nm = mem2 * alpha + oma * h2 - Bth * s2;
            mem2 = (mk2 == 0.0f) ? mem2 : nm;
            s2 = (mem2 - Bth > 0.0f) ? mk2 : 0.0f;
            ball = __ballot(s2 != 0.0f);
            if (lane == 0) wcnt[wid8] = __popcll(ball);
        }
        __syncthreads();                                        // B5
        {
            int basew = 0, tot = 0;
#pragma unroll
            for (int w = 0; w < 8; ++w) {
                int c = wcnt[w];
                if (w < wid8) basew += c;
                tot += c;
            }
            if (!half && s2 != 0.0f) {
                int pre = __popcll(ball & ((1ull << lane) - 1ull));
                list2[basew + pre] = j << 9;
            }
            na2 = tot;
        }
        __syncthreads();                                        // B6

        // ======== layer 3: h3 = s2_new@Wi3^T + bs3 ========
        int sp2n = na2 >> 1;
        float g3 = half ? gather8(WTi3j, list2, sp2n, na2)
                        : gather8(WTi3j, list2, 0, sp2n);
        if (half) part[2][j] = g3;
        __syncthreads();                                        // B7
        if (!half) {
            float h3 = bs3 + g3 + part[2][j];
            b3 = ro3 * b3 + omr3 * s3;
            float Bth = 0.01f + 1.8f * b3;
            float nm = mem3 * alpha + oma * h3 - Bth * s3;
            mem3 = (mk3 == 0.0f) ? mem3 : nm;
            s3 = (mem3 - Bth > 0.0f) ? mk3 : 0.0f;
            cnt3 += s3;   // defer output GEMV
        }
        // part[0] not rewritten until half1 finishes next step's gather1,
        // which is after it passes B3..B7 of this step -> no extra barrier.
    }

    // ---- output: out[n,o] = (Wo[o,:]·cnt3 + T*bo[o]) / T ----
    if (!half) part[0][j] = cnt3;
    __syncthreads();
    int wv = tid >> 6;   // 0..15
    for (int o = wv; o < 10; o += 16) {
        float p = 0.0f;
        for (int i = lane; i < H; i += 64)
            p += Wo[o * H + i] * part[0][i];
        for (int off = 32; off > 0; off >>= 1)
            p += __shfl_down(p, off);
        if (lane == 0)
            out[n * 10 + o] = (p + 196.0f * bo[o]) / 196.0f;
    }
}

extern "C" void kernel_launch(void* const* d_in, const int* in_sizes, int n_in,
                              void* d_out, int out_size, void* d_ws, size_t ws_size,
                              hipStream_t stream)
{
    const float* x    = (const float*)d_in[0];
    const float* Wi1  = (const float*)d_in[1];
    const float* bi1  = (const float*)d_in[2];
    const float* Wh1  = (const float*)d_in[3];
    const float* bh1  = (const float*)d_in[4];
    const float* Wi2  = (const float*)d_in[5];
    const float* bi2  = (const float*)d_in[6];
    const float* Wh2  = (const float*)d_in[7];
    const float* bh2  = (const float*)d_in[8];
    const float* Wi3  = (const float*)d_in[9];
    const float* bi3  = (const float*)d_in[10];
    const float* Wo   = (const float*)d_in[11];
    const float* bo   = (const float*)d_in[12];
    const float* tau1 = (const float*)d_in[13];
    const float* tau2 = (const float*)d_in[14];
    const float* tau3 = (const float*)d_in[15];
    const float* m1   = (const float*)d_in[16];
    const float* m2   = (const float*)d_in[17];
    const float* m3   = (const float*)d_in[18];

    float* ws  = (float*)d_ws;
    float* out = (float*)d_out;

    // pre-pass: transpose the 4 recurrent/ff matrices + 3 masks into ws
    transpose4<<<dim3(16, 16, 4), dim3(32, 8, 1), 0, stream>>>(Wh1, Wi2, Wh2, Wi3, ws);
    maskT3<<<dim3((TSTEPS * H + 255) / 256, 1, 3), 256, 0, stream>>>(m1, m2, m3, ws + 1048576);

    // main persistent kernel: 1 sample per workgroup (256 WGs, 1024 thr, 16 waves)
    lsnn_main<<<NBATCH, 1024, 0, stream>>>(x, Wi1, bi1, bh1, bi2, bh2, bi3,
                                           Wo, bo, tau1, tau2, tau3, ws, out);
}